// Round 1
// baseline (978.739 us; speedup 1.0000x reference)
//
#include <hip/hip_runtime.h>
#include <math.h>

// ================= compile-time Clebsch-Gordan tables =================
constexpr double cfact(int n){ double r=1.0; for(int i=2;i<=n;++i) r*=(double)i; return r; }
constexpr double csqrt_(double x){ double g=(x>1.0)?x:1.0; for(int i=0;i<100;++i) g=0.5*(g+x/g); return g; }
constexpr double cg_coef_(int l1,int m1,int l2,int m2,int l,int m){
  double pre = csqrt_((double)(2*l+1)*cfact(l1+l2-l)*cfact(l1-l2+l)*cfact(-l1+l2+l)/cfact(l1+l2+l+1));
  pre = pre*csqrt_(cfact(l+m)*cfact(l-m)*cfact(l1-m1)*cfact(l1+m1)*cfact(l2-m2)*cfact(l2+m2));
  double s=0.0;
  for(int k=0;k<=l1+l2-l;++k){
    int d0=k,d1=l1+l2-l-k,d2=l1-m1-k,d3=l2+m2-k,d4=l-l2+m1+k,d5=l-l1-m2+k;
    if(d0<0||d1<0||d2<0||d3<0||d4<0||d5<0) continue;
    double den=cfact(d0)*cfact(d1)*cfact(d2)*cfact(d3)*cfact(d4)*cfact(d5);
    s+=((k&1)?-1.0:1.0)/den;
  }
  return pre*s;
}
struct CGList{ int n; float coef[64]; int mi[64]; int ni[64]; int pi[64]; };
constexpr CGList build_cg(int l1,int l2,int l){
  CGList T{};
  for(int i=0;i<2*l1+1;++i){
    for(int j=0;j<2*l2+1;++j){
      int m1=i-l1, m2=j-l2, m=m1+m2;
      if(m<-l||m>l) continue;
      double c=cg_coef_(l1,m1,l2,m2,l,m);
      if(c>1e-12||c<-1e-12){
        T.coef[T.n]=(float)c; T.mi[T.n]=i; T.ni[T.n]=j; T.pi[T.n]=m+l; T.n++;
      }
    }
  }
  return T;
}

// ================= layout constants =================
// activation/output row offsets per l (rows of 256-row complex matrix)
__device__ __host__ constexpr int AOFF(int l){ return l==0?0: l==1?16: l==2?64:144; }
__device__ __host__ constexpr int MLs(int l){ return l==0?1024: l==1?1536: l==2?1792:1536; }
__device__ __host__ constexpr int WOFF(int l){ return l==0?0: l==1?16384: l==2?40960:69632; }
__device__ __host__ constexpr int SOFF(int l){ return l==0?0: l==1?1024: l==2?2560:4352; }

#define DEVFN __device__ __forceinline__

// accumulate complex CG product: mid[p] += cg[m,n,p] * (F1[m] * F2[n])
template<int L1,int L2,int L>
DEVFN void cg_accum(const float2* F1, const float2* F2, float2* mid){
  constexpr CGList T = build_cg(L1,L2,L);
  #pragma unroll
  for(int e=0;e<T.n;++e){
    const float c = T.coef[e];
    const float2 a = F1[T.mi[e]];
    const float2 b = F2[T.ni[e]];
    float pr = a.x*b.x - a.y*b.y;
    float pim= a.x*b.y + a.y*b.x;
    mid[T.pi[e]].x += c*pr;
    mid[T.pi[e]].y += c*pim;
  }
}

// ================= K1: per-channel sum of |mid|^2 over (b,p) =================
template<int L1,int L2,int L>
DEVFN float k1_body(const float2* __restrict__ act2, int b0, int t, int s){
  constexpr int N1=2*L1+1, N2=2*L2+1, NP=2*L+1;
  float ss=0.f;
  for(int bi=0;bi<32;++bi){
    const float2* arow = act2 + (size_t)(b0+bi)*256;
    float2 F1[N1], F2[N2], mid[NP];
    #pragma unroll
    for(int m=0;m<N1;++m) F1[m]=arow[AOFF(L1)+t*N1+m];
    #pragma unroll
    for(int n=0;n<N2;++n) F2[n]=arow[AOFF(L2)+s*N2+n];
    #pragma unroll
    for(int p=0;p<NP;++p) mid[p]=make_float2(0.f,0.f);
    cg_accum<L1,L2,L>(F1,F2,mid);
    #pragma unroll
    for(int p=0;p<NP;++p) ss += mid[p].x*mid[p].x + mid[p].y*mid[p].y;
  }
  return ss;
}

__global__ __launch_bounds__(256) void k_sumsq(const float* __restrict__ act, float* __restrict__ sumsq){
  int bid=blockIdx.x;            // 23 triples * 64 chunks = 1472 blocks
  int ti = bid>>6;
  int b0 = (bid&63)*32;
  int t = threadIdx.x>>4, s = threadIdx.x&15;
  const float2* act2=(const float2*)act;
  float ss=0.f;
  switch(ti){
    case 0:  ss=k1_body<0,0,0>(act2,b0,t,s); break;
    case 1:  ss=k1_body<1,1,0>(act2,b0,t,s); break;
    case 2:  ss=k1_body<2,2,0>(act2,b0,t,s); break;
    case 3:  ss=k1_body<3,3,0>(act2,b0,t,s); break;
    case 4:  ss=k1_body<1,0,1>(act2,b0,t,s); break;
    case 5:  ss=k1_body<1,1,1>(act2,b0,t,s); break;
    case 6:  ss=k1_body<2,1,1>(act2,b0,t,s); break;
    case 7:  ss=k1_body<2,2,1>(act2,b0,t,s); break;
    case 8:  ss=k1_body<3,2,1>(act2,b0,t,s); break;
    case 9:  ss=k1_body<3,3,1>(act2,b0,t,s); break;
    case 10: ss=k1_body<1,1,2>(act2,b0,t,s); break;
    case 11: ss=k1_body<2,0,2>(act2,b0,t,s); break;
    case 12: ss=k1_body<2,1,2>(act2,b0,t,s); break;
    case 13: ss=k1_body<2,2,2>(act2,b0,t,s); break;
    case 14: ss=k1_body<3,1,2>(act2,b0,t,s); break;
    case 15: ss=k1_body<3,2,2>(act2,b0,t,s); break;
    case 16: ss=k1_body<3,3,2>(act2,b0,t,s); break;
    case 17: ss=k1_body<2,1,3>(act2,b0,t,s); break;
    case 18: ss=k1_body<2,2,3>(act2,b0,t,s); break;
    case 19: ss=k1_body<3,0,3>(act2,b0,t,s); break;
    case 20: ss=k1_body<3,1,3>(act2,b0,t,s); break;
    case 21: ss=k1_body<3,2,3>(act2,b0,t,s); break;
    default: ss=k1_body<3,3,3>(act2,b0,t,s); break;
  }
  atomicAdd(&sumsq[ti*256 + threadIdx.x], ss);
}

// ================= K2: per-channel scale =================
__global__ __launch_bounds__(256) void k_scale(const float* __restrict__ bn,
                                               const float* __restrict__ sumsq,
                                               float* __restrict__ scale){
  int idx = blockIdx.x*256 + threadIdx.x;   // 23 blocks -> 5888
  if(idx>=5888) return;
  int l = (idx<1024)?0 : (idx<2560)?1 : (idx<4352)?2 : 3;
  float divi = (l==0)?(1.f/2048.f) : (l==1)?(1.f/6144.f) : (l==2)?(1.f/10240.f) : (1.f/14336.f);
  float bstd = sqrtf(sumsq[idx]*divi);
  float nstd = 0.5f*(bn[idx]+bstd);
  scale[idx] = 1.f/(nstd+1e-5f);
}

// ================= K3: output contraction =================
template<int L1,int L2,int L>
DEVFN void do_pair(int q, const float2* __restrict__ arow,
                   const float2* __restrict__ wl, const float* __restrict__ scl_l,
                   float2* mid_sm, float2* acc, int o, int sub){
  constexpr int N1=2*L1+1, N2=2*L2+1, NP=2*L+1;
  const int tid = o*16+sub;           // t = o, s = sub -> channel = t*16+s = tid
  float2 F1[N1], F2[N2], mid[NP];
  #pragma unroll
  for(int m=0;m<N1;++m) F1[m]=arow[AOFF(L1)+o*N1+m];
  #pragma unroll
  for(int n=0;n<N2;++n) F2[n]=arow[AOFF(L2)+sub*N2+n];
  #pragma unroll
  for(int p=0;p<NP;++p) mid[p]=make_float2(0.f,0.f);
  cg_accum<L1,L2,L>(F1,F2,mid);
  __syncthreads();                    // previous pair's reads done
  #pragma unroll
  for(int p=0;p<NP;++p) mid_sm[tid*NP+p]=mid[p];
  __syncthreads();
  const float2* wb = wl + q*256;
  const float*  sb = scl_l + q*256;
  for(int i=0;i<16;++i){
    int c = i*16 + sub;               // sub-lanes -> distinct LDS banks, coalesced W
    float sc = sb[c];
    float2 w = wb[c];
    w.x *= sc; w.y *= sc;
    #pragma unroll
    for(int p=0;p<NP;++p){
      float2 md = mid_sm[c*NP+p];
      acc[p].x += w.x*md.x - w.y*md.y;
      acc[p].y += w.x*md.y + w.y*md.x;
    }
  }
}

template<int L>
DEVFN void k3_body(int b, const float2* __restrict__ act2, const float2* __restrict__ W2,
                   const float* __restrict__ scale, float2* __restrict__ out2, float2* mid_sm){
  constexpr int NP=2*L+1;
  const int tid=threadIdx.x, o=tid>>4, sub=tid&15;
  const float2* arow = act2 + (size_t)b*256;
  const float2* wl   = W2 + WOFF(L) + o*MLs(L);
  const float*  scl  = scale + SOFF(L);
  float2 acc[NP];
  #pragma unroll
  for(int p=0;p<NP;++p) acc[p]=make_float2(0.f,0.f);
  if constexpr(L==0){
    do_pair<0,0,0>(0,arow,wl,scl,mid_sm,acc,o,sub);
    do_pair<1,1,0>(1,arow,wl,scl,mid_sm,acc,o,sub);
    do_pair<2,2,0>(2,arow,wl,scl,mid_sm,acc,o,sub);
    do_pair<3,3,0>(3,arow,wl,scl,mid_sm,acc,o,sub);
  } else if constexpr(L==1){
    do_pair<1,0,1>(0,arow,wl,scl,mid_sm,acc,o,sub);
    do_pair<1,1,1>(1,arow,wl,scl,mid_sm,acc,o,sub);
    do_pair<2,1,1>(2,arow,wl,scl,mid_sm,acc,o,sub);
    do_pair<2,2,1>(3,arow,wl,scl,mid_sm,acc,o,sub);
    do_pair<3,2,1>(4,arow,wl,scl,mid_sm,acc,o,sub);
    do_pair<3,3,1>(5,arow,wl,scl,mid_sm,acc,o,sub);
  } else if constexpr(L==2){
    do_pair<1,1,2>(0,arow,wl,scl,mid_sm,acc,o,sub);
    do_pair<2,0,2>(1,arow,wl,scl,mid_sm,acc,o,sub);
    do_pair<2,1,2>(2,arow,wl,scl,mid_sm,acc,o,sub);
    do_pair<2,2,2>(3,arow,wl,scl,mid_sm,acc,o,sub);
    do_pair<3,1,2>(4,arow,wl,scl,mid_sm,acc,o,sub);
    do_pair<3,2,2>(5,arow,wl,scl,mid_sm,acc,o,sub);
    do_pair<3,3,2>(6,arow,wl,scl,mid_sm,acc,o,sub);
  } else {
    do_pair<2,1,3>(0,arow,wl,scl,mid_sm,acc,o,sub);
    do_pair<2,2,3>(1,arow,wl,scl,mid_sm,acc,o,sub);
    do_pair<3,0,3>(2,arow,wl,scl,mid_sm,acc,o,sub);
    do_pair<3,1,3>(3,arow,wl,scl,mid_sm,acc,o,sub);
    do_pair<3,2,3>(4,arow,wl,scl,mid_sm,acc,o,sub);
    do_pair<3,3,3>(5,arow,wl,scl,mid_sm,acc,o,sub);
  }
  // reduce over the 16 sub-lanes (within-wave 16-lane groups)
  #pragma unroll
  for(int p=0;p<NP;++p){
    #pragma unroll
    for(int msk=8;msk>=1;msk>>=1){
      acc[p].x += __shfl_xor(acc[p].x, msk);
      acc[p].y += __shfl_xor(acc[p].y, msk);
    }
  }
  if(sub==0){
    #pragma unroll
    for(int p=0;p<NP;++p) out2[(size_t)b*256 + AOFF(L) + o*NP + p] = acc[p];
  }
}

__global__ __launch_bounds__(256) void k_out(const float* __restrict__ act,
                                             const float* __restrict__ W,
                                             const float* __restrict__ scale,
                                             float* __restrict__ out){
  __shared__ float2 mid_sm[256*7];
  int bid=blockIdx.x;          // 8192 = 2048 b * 4 l, interleaved for balance
  int l = bid & 3;
  int b = bid >> 2;
  const float2* act2=(const float2*)act;
  const float2* W2=(const float2*)W;
  float2* out2=(float2*)out;
  switch(l){
    case 0: k3_body<0>(b,act2,W2,scale,out2,mid_sm); break;
    case 1: k3_body<1>(b,act2,W2,scale,out2,mid_sm); break;
    case 2: k3_body<2>(b,act2,W2,scale,out2,mid_sm); break;
    default:k3_body<3>(b,act2,W2,scale,out2,mid_sm); break;
  }
}

// ================= host launch =================
extern "C" void kernel_launch(void* const* d_in, const int* in_sizes, int n_in,
                              void* d_out, int out_size, void* d_ws, size_t ws_size,
                              hipStream_t stream) {
  const float* act = (const float*)d_in[0];   // (2048,256,2) f32
  const float* W   = (const float*)d_in[1];   // (94208,2) f32
  const float* bn  = (const float*)d_in[2];   // (5888,) f32
  float* out = (float*)d_out;                 // (2048,256,2) f32

  float* sumsq = (float*)d_ws;                            // 5888 f32
  float* scale = (float*)((char*)d_ws + 24576);           // 5888 f32

  hipMemsetAsync(sumsq, 0, 5888*sizeof(float), stream);
  hipLaunchKernelGGL(k_sumsq, dim3(23*64), dim3(256), 0, stream, act, sumsq);
  hipLaunchKernelGGL(k_scale, dim3(23),    dim3(256), 0, stream, bn, sumsq, scale);
  hipLaunchKernelGGL(k_out,   dim3(8192),  dim3(256), 0, stream, act, W, scale, out);
}

// Round 2
// 240.982 us; speedup vs baseline: 4.0615x; 4.0615x over previous
//
#include <hip/hip_runtime.h>
#include <math.h>

typedef __attribute__((ext_vector_type(8))) short bf16x8;
typedef __attribute__((ext_vector_type(4))) float f32x4;

// ================= compile-time Clebsch-Gordan tables =================
constexpr double cfact(int n){ double r=1.0; for(int i=2;i<=n;++i) r*=(double)i; return r; }
constexpr double csqrt_(double x){ double g=(x>1.0)?x:1.0; for(int i=0;i<100;++i) g=0.5*(g+x/g); return g; }
constexpr double cg_coef_(int l1,int m1,int l2,int m2,int l,int m){
  double pre = csqrt_((double)(2*l+1)*cfact(l1+l2-l)*cfact(l1-l2+l)*cfact(-l1+l2+l)/cfact(l1+l2+l+1));
  pre = pre*csqrt_(cfact(l+m)*cfact(l-m)*cfact(l1-m1)*cfact(l1+m1)*cfact(l2-m2)*cfact(l2+m2));
  double s=0.0;
  for(int k=0;k<=l1+l2-l;++k){
    int d0=k,d1=l1+l2-l-k,d2=l1-m1-k,d3=l2+m2-k,d4=l-l2+m1+k,d5=l-l1-m2+k;
    if(d0<0||d1<0||d2<0||d3<0||d4<0||d5<0) continue;
    double den=cfact(d0)*cfact(d1)*cfact(d2)*cfact(d3)*cfact(d4)*cfact(d5);
    s+=((k&1)?-1.0:1.0)/den;
  }
  return pre*s;
}
struct CGList{ int n; float coef[64]; int mi[64]; int ni[64]; int pi[64]; };
constexpr CGList build_cg(int l1,int l2,int l){
  CGList T{};
  for(int i=0;i<2*l1+1;++i){
    for(int j=0;j<2*l2+1;++j){
      int m1=i-l1, m2=j-l2, m=m1+m2;
      if(m<-l||m>l) continue;
      double c=cg_coef_(l1,m1,l2,m2,l,m);
      if(c>1e-12||c<-1e-12){
        T.coef[T.n]=(float)c; T.mi[T.n]=i; T.ni[T.n]=j; T.pi[T.n]=m+l; T.n++;
      }
    }
  }
  return T;
}

// ================= layout constants =================
__device__ __host__ constexpr int AOFF(int l){ return l==0?0: l==1?16: l==2?64:144; }
__device__ __host__ constexpr int MLs(int l){ return l==0?1024: l==1?1536: l==2?1792:1536; }
__device__ __host__ constexpr int WOFF(int l){ return l==0?0: l==1?16384: l==2?40960:69632; }
__device__ __host__ constexpr int SOFF(int l){ return l==0?0: l==1?1024: l==2?2560:4352; }
__device__ __host__ constexpr int NTRI(int l){ return l==0?4: l==1?6: l==2?7:6; }
// A-matrix (bf16) base offsets per l, in elements: 32 rows x 2*Ml cols
__device__ __host__ constexpr int ABASE(int l){ return l==0?0: l==1?65536: l==2?163840:278528; }

#define DEVFN __device__ __forceinline__

DEVFN unsigned f2bf2(float x, float y){
  unsigned ux = __float_as_uint(x); ux = (ux + 0x7FFFu + ((ux>>16)&1u)) >> 16;
  unsigned uy = __float_as_uint(y); uy = (uy + 0x7FFFu + ((uy>>16)&1u)) >> 16;
  return (ux & 0xFFFFu) | (uy << 16);
}

// accumulate complex CG product: mid[p] += cg[m,n,p] * (F1[m] * F2[n])
template<int L1,int L2,int L>
DEVFN void cg_accum(const float2* F1, const float2* F2, float2* mid){
  constexpr CGList T = build_cg(L1,L2,L);
  #pragma unroll
  for(int e=0;e<T.n;++e){
    const float c = T.coef[e];
    const float2 a = F1[T.mi[e]];
    const float2 b = F2[T.ni[e]];
    float pr = a.x*b.x - a.y*b.y;
    float pim= a.x*b.y + a.y*b.x;
    mid[T.pi[e]].x += c*pr;
    mid[T.pi[e]].y += c*pim;
  }
}

// ================= K1: per-channel sum of |mid|^2 over (b,p) =================
template<int L1,int L2,int L>
DEVFN float k1_body(const float2* __restrict__ act2, int b0, int t, int s){
  constexpr int N1=2*L1+1, N2=2*L2+1, NP=2*L+1;
  float ss=0.f;
  for(int bi=0;bi<32;++bi){
    const float2* arow = act2 + (size_t)(b0+bi)*256;
    float2 F1[N1], F2[N2], mid[NP];
    #pragma unroll
    for(int m=0;m<N1;++m) F1[m]=arow[AOFF(L1)+t*N1+m];
    #pragma unroll
    for(int n=0;n<N2;++n) F2[n]=arow[AOFF(L2)+s*N2+n];
    #pragma unroll
    for(int p=0;p<NP;++p) mid[p]=make_float2(0.f,0.f);
    cg_accum<L1,L2,L>(F1,F2,mid);
    #pragma unroll
    for(int p=0;p<NP;++p) ss += mid[p].x*mid[p].x + mid[p].y*mid[p].y;
  }
  return ss;
}

__global__ __launch_bounds__(256) void k_sumsq(const float* __restrict__ act, float* __restrict__ sumsq){
  int bid=blockIdx.x;            // 23 triples * 64 chunks = 1472 blocks
  int ti = bid>>6;
  int b0 = (bid&63)*32;
  int t = threadIdx.x>>4, s = threadIdx.x&15;
  const float2* act2=(const float2*)act;
  float ss=0.f;
  switch(ti){
    case 0:  ss=k1_body<0,0,0>(act2,b0,t,s); break;
    case 1:  ss=k1_body<1,1,0>(act2,b0,t,s); break;
    case 2:  ss=k1_body<2,2,0>(act2,b0,t,s); break;
    case 3:  ss=k1_body<3,3,0>(act2,b0,t,s); break;
    case 4:  ss=k1_body<1,0,1>(act2,b0,t,s); break;
    case 5:  ss=k1_body<1,1,1>(act2,b0,t,s); break;
    case 6:  ss=k1_body<2,1,1>(act2,b0,t,s); break;
    case 7:  ss=k1_body<2,2,1>(act2,b0,t,s); break;
    case 8:  ss=k1_body<3,2,1>(act2,b0,t,s); break;
    case 9:  ss=k1_body<3,3,1>(act2,b0,t,s); break;
    case 10: ss=k1_body<1,1,2>(act2,b0,t,s); break;
    case 11: ss=k1_body<2,0,2>(act2,b0,t,s); break;
    case 12: ss=k1_body<2,1,2>(act2,b0,t,s); break;
    case 13: ss=k1_body<2,2,2>(act2,b0,t,s); break;
    case 14: ss=k1_body<3,1,2>(act2,b0,t,s); break;
    case 15: ss=k1_body<3,2,2>(act2,b0,t,s); break;
    case 16: ss=k1_body<3,3,2>(act2,b0,t,s); break;
    case 17: ss=k1_body<2,1,3>(act2,b0,t,s); break;
    case 18: ss=k1_body<2,2,3>(act2,b0,t,s); break;
    case 19: ss=k1_body<3,0,3>(act2,b0,t,s); break;
    case 20: ss=k1_body<3,1,3>(act2,b0,t,s); break;
    case 21: ss=k1_body<3,2,3>(act2,b0,t,s); break;
    default: ss=k1_body<3,3,3>(act2,b0,t,s); break;
  }
  atomicAdd(&sumsq[ti*256 + threadIdx.x], ss);
}

// ================= K2: per-channel scale =================
__global__ __launch_bounds__(256) void k_scale(const float* __restrict__ bn,
                                               const float* __restrict__ sumsq,
                                               float* __restrict__ scale){
  int idx = blockIdx.x*256 + threadIdx.x;   // 23 blocks -> 5888
  if(idx>=5888) return;
  int l = (idx<1024)?0 : (idx<2560)?1 : (idx<4352)?2 : 3;
  float divi = (l==0)?(1.f/2048.f) : (l==1)?(1.f/6144.f) : (l==2)?(1.f/10240.f) : (1.f/14336.f);
  float bstd = sqrtf(sumsq[idx]*divi);
  float nstd = 0.5f*(bn[idx]+bstd);
  scale[idx] = 1.f/(nstd+1e-5f);
}

// ================= K2b: build bf16 A matrices (scale folded into W) ======
// A_l is [32][2*Ml] bf16 row-major. Rows 0..15 (o): k=2c -> w.x*s, k=2c+1 -> -w.y*s
// Rows 16..31 (o):                         k=2c -> w.y*s, k=2c+1 ->  w.x*s
__global__ __launch_bounds__(256) void k_buildA(const float* __restrict__ W,
                                                const float* __restrict__ scale,
                                                short* __restrict__ A){
  int idx = blockIdx.x*256 + threadIdx.x;   // 5888 channels
  if(idx>=5888) return;
  int l = (idx<1024)?0 : (idx<2560)?1 : (idx<4352)?2 : 3;
  int c = idx - SOFF(l);
  int Ml = MLs(l);
  float s = scale[idx];
  const float2* wbase = (const float2*)W + WOFF(l) + c;
  unsigned* Aw = (unsigned*)(A + ABASE(l));   // row pitch = Ml words (2*Ml bf16)
  for(int o=0;o<16;++o){
    float2 w = wbase[(size_t)o*Ml];
    Aw[(size_t)o*Ml + c]      = f2bf2(w.x*s, -w.y*s);
    Aw[(size_t)(o+16)*Ml + c] = f2bf2(w.y*s,  w.x*s);
  }
}

// ================= K3: fused mid-recompute + MFMA GEMM =================
// Block: one l, n-window [n0, n0+64) of n=(b*NP+p). Loops over all triples
// of l in k-chunks of 256 (128 channels). Phase1 computes mid -> LDS bf16
// tile [64 n][264 k(padded)]; Phase2: 4 waves x (1 n-subtile x 2 m-tiles)
// mfma_f32_16x16x32_bf16, full-K accumulation, direct store.
template<int L1,int L2,int L>
DEVFN void phase1(const float2* __restrict__ act2, unsigned* ldsw,
                  int t, int s, int b_lo, int b_hi, int bh, int n0, int c_local){
  constexpr int N1=2*L1+1, N2=2*L2+1, NP=2*L+1;
  for(int b = b_lo + bh; b <= b_hi; b += 2){
    const float2* arow = act2 + (size_t)b*256;
    float2 F1[N1], F2[N2], mid[NP];
    #pragma unroll
    for(int m=0;m<N1;++m) F1[m]=arow[AOFF(L1)+t*N1+m];
    #pragma unroll
    for(int n=0;n<N2;++n) F2[n]=arow[AOFF(L2)+s*N2+n];
    #pragma unroll
    for(int p=0;p<NP;++p) mid[p]=make_float2(0.f,0.f);
    cg_accum<L1,L2,L>(F1,F2,mid);
    int nb = b*NP - n0;
    #pragma unroll
    for(int p=0;p<NP;++p){
      int n = nb + p;
      if(n>=0 && n<64) ldsw[n*132 + c_local] = f2bf2(mid[p].x, mid[p].y);
    }
  }
}

template<int L>
DEVFN void p1_dispatch(int q, const float2* __restrict__ act2, unsigned* ldsw,
                       int t,int s,int b_lo,int b_hi,int bh,int n0,int c_local){
  if constexpr(L==0){
    switch(q){
      case 0: phase1<0,0,0>(act2,ldsw,t,s,b_lo,b_hi,bh,n0,c_local); break;
      case 1: phase1<1,1,0>(act2,ldsw,t,s,b_lo,b_hi,bh,n0,c_local); break;
      case 2: phase1<2,2,0>(act2,ldsw,t,s,b_lo,b_hi,bh,n0,c_local); break;
      default:phase1<3,3,0>(act2,ldsw,t,s,b_lo,b_hi,bh,n0,c_local); break;
    }
  } else if constexpr(L==1){
    switch(q){
      case 0: phase1<1,0,1>(act2,ldsw,t,s,b_lo,b_hi,bh,n0,c_local); break;
      case 1: phase1<1,1,1>(act2,ldsw,t,s,b_lo,b_hi,bh,n0,c_local); break;
      case 2: phase1<2,1,1>(act2,ldsw,t,s,b_lo,b_hi,bh,n0,c_local); break;
      case 3: phase1<2,2,1>(act2,ldsw,t,s,b_lo,b_hi,bh,n0,c_local); break;
      case 4: phase1<3,2,1>(act2,ldsw,t,s,b_lo,b_hi,bh,n0,c_local); break;
      default:phase1<3,3,1>(act2,ldsw,t,s,b_lo,b_hi,bh,n0,c_local); break;
    }
  } else if constexpr(L==2){
    switch(q){
      case 0: phase1<1,1,2>(act2,ldsw,t,s,b_lo,b_hi,bh,n0,c_local); break;
      case 1: phase1<2,0,2>(act2,ldsw,t,s,b_lo,b_hi,bh,n0,c_local); break;
      case 2: phase1<2,1,2>(act2,ldsw,t,s,b_lo,b_hi,bh,n0,c_local); break;
      case 3: phase1<2,2,2>(act2,ldsw,t,s,b_lo,b_hi,bh,n0,c_local); break;
      case 4: phase1<3,1,2>(act2,ldsw,t,s,b_lo,b_hi,bh,n0,c_local); break;
      case 5: phase1<3,2,2>(act2,ldsw,t,s,b_lo,b_hi,bh,n0,c_local); break;
      default:phase1<3,3,2>(act2,ldsw,t,s,b_lo,b_hi,bh,n0,c_local); break;
    }
  } else {
    switch(q){
      case 0: phase1<2,1,3>(act2,ldsw,t,s,b_lo,b_hi,bh,n0,c_local); break;
      case 1: phase1<2,2,3>(act2,ldsw,t,s,b_lo,b_hi,bh,n0,c_local); break;
      case 2: phase1<3,0,3>(act2,ldsw,t,s,b_lo,b_hi,bh,n0,c_local); break;
      case 3: phase1<3,1,3>(act2,ldsw,t,s,b_lo,b_hi,bh,n0,c_local); break;
      case 4: phase1<3,2,3>(act2,ldsw,t,s,b_lo,b_hi,bh,n0,c_local); break;
      default:phase1<3,3,3>(act2,ldsw,t,s,b_lo,b_hi,bh,n0,c_local); break;
    }
  }
}

template<int L>
DEVFN void k3_gemm(int n0, const float2* __restrict__ act2,
                   const short* __restrict__ A_l, float* __restrict__ out,
                   unsigned* ldsw){
  constexpr int NP = 2*L+1;
  constexpr int NT = NTRI(L);
  constexpr int pitch = 2*MLs(L);          // A row pitch in bf16 elements
  const int tid = threadIdx.x;
  const int lane = tid & 63, wsub = tid >> 6;
  const int col = lane & 15, quad = lane >> 4;
  const int c_local = tid & 127, bh = tid >> 7;
  const int b_lo = n0 / NP;
  const int b_hi = (n0 + 63) / NP;

  f32x4 cR = {0.f,0.f,0.f,0.f};
  f32x4 cI = {0.f,0.f,0.f,0.f};

  const short* Ar0 = A_l + (size_t)col      * pitch + quad*8;
  const short* Ar1 = A_l + (size_t)(col+16) * pitch + quad*8;
  const char*  ldsb = (const char*)ldsw + (wsub*16 + col)*528 + quad*16;

  for(int chunk = 0; chunk < 2*NT; ++chunk){
    const int q = chunk >> 1, half = chunk & 1;
    const int ch = half*128 + c_local;     // channel within triple
    const int t = ch >> 4, s = ch & 15;
    __syncthreads();                       // LDS tile free for rewrite
    p1_dispatch<L>(q, act2, ldsw, t, s, b_lo, b_hi, bh, n0, c_local);
    __syncthreads();
    const int kbase = q*512 + half*256;    // A column base (bf16 elements)
    #pragma unroll
    for(int ks=0; ks<8; ++ks){
      bf16x8 a0 = *(const bf16x8*)(Ar0 + kbase + ks*32);
      bf16x8 a1 = *(const bf16x8*)(Ar1 + kbase + ks*32);
      bf16x8 bb = *(const bf16x8*)(ldsb + ks*64);
      cR = __builtin_amdgcn_mfma_f32_16x16x32_bf16(a0, bb, cR, 0, 0, 0);
      cI = __builtin_amdgcn_mfma_f32_16x16x32_bf16(a1, bb, cI, 0, 0, 0);
    }
  }
  // epilogue: D col = lane&15 -> n, row = quad*4+reg -> o; mt0=real, mt1=imag
  const int n = n0 + wsub*16 + col;
  const int b = n / NP, p = n % NP;
  float2* out2 = (float2*)out;
  #pragma unroll
  for(int i=0;i<4;++i){
    const int o = quad*4 + i;
    out2[(size_t)b*256 + AOFF(L) + o*NP + p] = make_float2(cR[i], cI[i]);
  }
}

__global__ __launch_bounds__(256) void k_gemm(const float* __restrict__ act,
                                              const short* __restrict__ A,
                                              float* __restrict__ out){
  __shared__ unsigned ldsw[64*132];        // 33792 B: [64 n][132 words(=264 bf16 k, pad 8)]
  const int bid = blockIdx.x;              // 512 = 32(l0)+96(l1)+160(l2)+224(l3)
  const float2* act2 = (const float2*)act;
  if(bid < 32)       k3_gemm<0>((bid      )*64, act2, A + ABASE(0), out, ldsw);
  else if(bid < 128) k3_gemm<1>((bid - 32 )*64, act2, A + ABASE(1), out, ldsw);
  else if(bid < 288) k3_gemm<2>((bid - 128)*64, act2, A + ABASE(2), out, ldsw);
  else               k3_gemm<3>((bid - 288)*64, act2, A + ABASE(3), out, ldsw);
}

// ================= host launch =================
extern "C" void kernel_launch(void* const* d_in, const int* in_sizes, int n_in,
                              void* d_out, int out_size, void* d_ws, size_t ws_size,
                              hipStream_t stream) {
  const float* act = (const float*)d_in[0];   // (2048,256,2) f32
  const float* W   = (const float*)d_in[1];   // (94208,2) f32
  const float* bn  = (const float*)d_in[2];   // (5888,) f32
  float* out = (float*)d_out;                 // (2048,256,2) f32

  float* sumsq = (float*)d_ws;                          // 5888 f32
  float* scale = (float*)((char*)d_ws + 24576);         // 5888 f32
  short* A     = (short*)((char*)d_ws + 49152);         // 376832 bf16 (754 KB)

  hipMemsetAsync(sumsq, 0, 5888*sizeof(float), stream);
  hipLaunchKernelGGL(k_sumsq,  dim3(23*64), dim3(256), 0, stream, act, sumsq);
  hipLaunchKernelGGL(k_scale,  dim3(23),    dim3(256), 0, stream, bn, sumsq, scale);
  hipLaunchKernelGGL(k_buildA, dim3(23),    dim3(256), 0, stream, W, scale, A);
  hipLaunchKernelGGL(k_gemm,   dim3(512),   dim3(256), 0, stream, act, A, out);
}

// Round 3
// 210.419 us; speedup vs baseline: 4.6514x; 1.1452x over previous
//
#include <hip/hip_runtime.h>
#include <math.h>

typedef __attribute__((ext_vector_type(8))) short bf16x8;
typedef __attribute__((ext_vector_type(4))) float f32x4;

// ================= compile-time Clebsch-Gordan tables =================
constexpr double cfact(int n){ double r=1.0; for(int i=2;i<=n;++i) r*=(double)i; return r; }
constexpr double csqrt_(double x){ double g=(x>1.0)?x:1.0; for(int i=0;i<100;++i) g=0.5*(g+x/g); return g; }
constexpr double cg_coef_(int l1,int m1,int l2,int m2,int l,int m){
  double pre = csqrt_((double)(2*l+1)*cfact(l1+l2-l)*cfact(l1-l2+l)*cfact(-l1+l2+l)/cfact(l1+l2+l+1));
  pre = pre*csqrt_(cfact(l+m)*cfact(l-m)*cfact(l1-m1)*cfact(l1+m1)*cfact(l2-m2)*cfact(l2+m2));
  double s=0.0;
  for(int k=0;k<=l1+l2-l;++k){
    int d0=k,d1=l1+l2-l-k,d2=l1-m1-k,d3=l2+m2-k,d4=l-l2+m1+k,d5=l-l1-m2+k;
    if(d0<0||d1<0||d2<0||d3<0||d4<0||d5<0) continue;
    double den=cfact(d0)*cfact(d1)*cfact(d2)*cfact(d3)*cfact(d4)*cfact(d5);
    s+=((k&1)?-1.0:1.0)/den;
  }
  return pre*s;
}
struct CGList{ int n; float coef[64]; int mi[64]; int ni[64]; int pi[64]; };
constexpr CGList build_cg(int l1,int l2,int l){
  CGList T{};
  for(int i=0;i<2*l1+1;++i){
    for(int j=0;j<2*l2+1;++j){
      int m1=i-l1, m2=j-l2, m=m1+m2;
      if(m<-l||m>l) continue;
      double c=cg_coef_(l1,m1,l2,m2,l,m);
      if(c>1e-12||c<-1e-12){
        T.coef[T.n]=(float)c; T.mi[T.n]=i; T.ni[T.n]=j; T.pi[T.n]=m+l; T.n++;
      }
    }
  }
  return T;
}

// ================= layout constants =================
__device__ __host__ constexpr int AOFF(int l){ return l==0?0: l==1?16: l==2?64:144; }
__device__ __host__ constexpr int MLs(int l){ return l==0?1024: l==1?1536: l==2?1792:1536; }
__device__ __host__ constexpr int WOFF(int l){ return l==0?0: l==1?16384: l==2?40960:69632; }
__device__ __host__ constexpr int SOFF(int l){ return l==0?0: l==1?1024: l==2?2560:4352; }
__device__ __host__ constexpr int NTRI(int l){ return l==0?4: l==1?6: l==2?7:6; }
__device__ __host__ constexpr int ABASE(int l){ return l==0?0: l==1?65536: l==2?163840:278528; }

#define DEVFN __device__ __forceinline__

// LDS tile: [32 n rows][144 words] per buffer (pitch 144: 144%32==16 ->
// even rows cover banks 0..15, odd rows 16..31 under the (col,quad) read
// pattern -> conflict-free b128 reads; phase-1 writes are stride-1 -> free)
#define LPITCH 144

DEVFN unsigned f2bf2(float x, float y){
  unsigned ux = __float_as_uint(x); ux = (ux + 0x7FFFu + ((ux>>16)&1u)) >> 16;
  unsigned uy = __float_as_uint(y); uy = (uy + 0x7FFFu + ((uy>>16)&1u)) >> 16;
  return (ux & 0xFFFFu) | (uy << 16);
}

template<int L1,int L2,int L>
DEVFN void cg_accum(const float2* F1, const float2* F2, float2* mid){
  constexpr CGList T = build_cg(L1,L2,L);
  #pragma unroll
  for(int e=0;e<T.n;++e){
    const float c = T.coef[e];
    const float2 a = F1[T.mi[e]];
    const float2 b = F2[T.ni[e]];
    float pr = a.x*b.x - a.y*b.y;
    float pim= a.x*b.y + a.y*b.x;
    mid[T.pi[e]].x += c*pr;
    mid[T.pi[e]].y += c*pim;
  }
}

// ================= K1: per-channel sum of |mid|^2 over (b,p) =================
template<int L1,int L2,int L>
DEVFN float k1_body(const float2* __restrict__ act2, int b0, int t, int s){
  constexpr int N1=2*L1+1, N2=2*L2+1, NP=2*L+1;
  float ss=0.f;
  for(int bi=0;bi<16;++bi){
    const float2* arow = act2 + (size_t)(b0+bi)*256;
    float2 F1[N1], F2[N2], mid[NP];
    #pragma unroll
    for(int m=0;m<N1;++m) F1[m]=arow[AOFF(L1)+t*N1+m];
    #pragma unroll
    for(int n=0;n<N2;++n) F2[n]=arow[AOFF(L2)+s*N2+n];
    #pragma unroll
    for(int p=0;p<NP;++p) mid[p]=make_float2(0.f,0.f);
    cg_accum<L1,L2,L>(F1,F2,mid);
    #pragma unroll
    for(int p=0;p<NP;++p) ss += mid[p].x*mid[p].x + mid[p].y*mid[p].y;
  }
  return ss;
}

__global__ __launch_bounds__(256) void k_sumsq(const float* __restrict__ act, float* __restrict__ sumsq){
  int bid=blockIdx.x;            // 23 triples * 128 chunks = 2944 blocks
  int ti = bid>>7;
  int b0 = (bid&127)*16;
  int t = threadIdx.x>>4, s = threadIdx.x&15;
  const float2* act2=(const float2*)act;
  float ss=0.f;
  switch(ti){
    case 0:  ss=k1_body<0,0,0>(act2,b0,t,s); break;
    case 1:  ss=k1_body<1,1,0>(act2,b0,t,s); break;
    case 2:  ss=k1_body<2,2,0>(act2,b0,t,s); break;
    case 3:  ss=k1_body<3,3,0>(act2,b0,t,s); break;
    case 4:  ss=k1_body<1,0,1>(act2,b0,t,s); break;
    case 5:  ss=k1_body<1,1,1>(act2,b0,t,s); break;
    case 6:  ss=k1_body<2,1,1>(act2,b0,t,s); break;
    case 7:  ss=k1_body<2,2,1>(act2,b0,t,s); break;
    case 8:  ss=k1_body<3,2,1>(act2,b0,t,s); break;
    case 9:  ss=k1_body<3,3,1>(act2,b0,t,s); break;
    case 10: ss=k1_body<1,1,2>(act2,b0,t,s); break;
    case 11: ss=k1_body<2,0,2>(act2,b0,t,s); break;
    case 12: ss=k1_body<2,1,2>(act2,b0,t,s); break;
    case 13: ss=k1_body<2,2,2>(act2,b0,t,s); break;
    case 14: ss=k1_body<3,1,2>(act2,b0,t,s); break;
    case 15: ss=k1_body<3,2,2>(act2,b0,t,s); break;
    case 16: ss=k1_body<3,3,2>(act2,b0,t,s); break;
    case 17: ss=k1_body<2,1,3>(act2,b0,t,s); break;
    case 18: ss=k1_body<2,2,3>(act2,b0,t,s); break;
    case 19: ss=k1_body<3,0,3>(act2,b0,t,s); break;
    case 20: ss=k1_body<3,1,3>(act2,b0,t,s); break;
    case 21: ss=k1_body<3,2,3>(act2,b0,t,s); break;
    default: ss=k1_body<3,3,3>(act2,b0,t,s); break;
  }
  atomicAdd(&sumsq[ti*256 + threadIdx.x], ss);
}

// ============ K2: scale + build bf16 A matrices (scale folded into W) =======
// A_l is [32][2*Ml] bf16 row-major. Rows 0..15 (o): k=2c -> w.x*s, k=2c+1 -> -w.y*s
// Rows 16..31 (o):                                  k=2c -> w.y*s, k=2c+1 ->  w.x*s
__global__ __launch_bounds__(256) void k_buildA(const float* __restrict__ W,
                                                const float* __restrict__ bn,
                                                const float* __restrict__ sumsq,
                                                short* __restrict__ A){
  int idx = blockIdx.x*256 + threadIdx.x;   // 5888 channels
  if(idx>=5888) return;
  int l = (idx<1024)?0 : (idx<2560)?1 : (idx<4352)?2 : 3;
  float divi = (l==0)?(1.f/2048.f) : (l==1)?(1.f/6144.f) : (l==2)?(1.f/10240.f) : (1.f/14336.f);
  float bstd = sqrtf(sumsq[idx]*divi);
  float nstd = 0.5f*(bn[idx]+bstd);
  float s = 1.f/(nstd+1e-5f);
  int c = idx - SOFF(l);
  int Ml = MLs(l);
  const float2* wbase = (const float2*)W + WOFF(l) + c;
  unsigned* Aw = (unsigned*)(A + ABASE(l));   // row pitch = Ml words (2*Ml bf16)
  for(int o=0;o<16;++o){
    float2 w = wbase[(size_t)o*Ml];
    Aw[(size_t)o*Ml + c]      = f2bf2(w.x*s, -w.y*s);
    Aw[(size_t)(o+16)*Ml + c] = f2bf2(w.y*s,  w.x*s);
  }
}

// ================= K3: fused mid-recompute + MFMA GEMM =================
// Block: one l, 32-wide n-window of n=(b*NP+p). Double-buffered LDS tile
// [32 n][144 words] (bf16 pair per word), ONE barrier per k-chunk.
// Wave roles: wsub&1 -> n-half, wsub>>1 -> real/imag row block of A.
template<int L1,int L2,int L>
DEVFN void phase1(const float2* __restrict__ act2, unsigned* ldsw,
                  int t, int s, int b_lo, int b_hi, int bh, int n0, int c_local){
  constexpr int N1=2*L1+1, N2=2*L2+1, NP=2*L+1;
  for(int b = b_lo + bh; b <= b_hi; b += 2){
    const float2* arow = act2 + (size_t)b*256;
    float2 F1[N1], F2[N2], mid[NP];
    #pragma unroll
    for(int m=0;m<N1;++m) F1[m]=arow[AOFF(L1)+t*N1+m];
    #pragma unroll
    for(int n=0;n<N2;++n) F2[n]=arow[AOFF(L2)+s*N2+n];
    #pragma unroll
    for(int p=0;p<NP;++p) mid[p]=make_float2(0.f,0.f);
    cg_accum<L1,L2,L>(F1,F2,mid);
    int nb = b*NP - n0;
    #pragma unroll
    for(int p=0;p<NP;++p){
      int n = nb + p;
      if(n>=0 && n<32) ldsw[n*LPITCH + c_local] = f2bf2(mid[p].x, mid[p].y);
    }
  }
}

template<int L>
DEVFN void p1_dispatch(int q, const float2* __restrict__ act2, unsigned* ldsw,
                       int t,int s,int b_lo,int b_hi,int bh,int n0,int c_local){
  if constexpr(L==0){
    switch(q){
      case 0: phase1<0,0,0>(act2,ldsw,t,s,b_lo,b_hi,bh,n0,c_local); break;
      case 1: phase1<1,1,0>(act2,ldsw,t,s,b_lo,b_hi,bh,n0,c_local); break;
      case 2: phase1<2,2,0>(act2,ldsw,t,s,b_lo,b_hi,bh,n0,c_local); break;
      default:phase1<3,3,0>(act2,ldsw,t,s,b_lo,b_hi,bh,n0,c_local); break;
    }
  } else if constexpr(L==1){
    switch(q){
      case 0: phase1<1,0,1>(act2,ldsw,t,s,b_lo,b_hi,bh,n0,c_local); break;
      case 1: phase1<1,1,1>(act2,ldsw,t,s,b_lo,b_hi,bh,n0,c_local); break;
      case 2: phase1<2,1,1>(act2,ldsw,t,s,b_lo,b_hi,bh,n0,c_local); break;
      case 3: phase1<2,2,1>(act2,ldsw,t,s,b_lo,b_hi,bh,n0,c_local); break;
      case 4: phase1<3,2,1>(act2,ldsw,t,s,b_lo,b_hi,bh,n0,c_local); break;
      default:phase1<3,3,1>(act2,ldsw,t,s,b_lo,b_hi,bh,n0,c_local); break;
    }
  } else if constexpr(L==2){
    switch(q){
      case 0: phase1<1,1,2>(act2,ldsw,t,s,b_lo,b_hi,bh,n0,c_local); break;
      case 1: phase1<2,0,2>(act2,ldsw,t,s,b_lo,b_hi,bh,n0,c_local); break;
      case 2: phase1<2,1,2>(act2,ldsw,t,s,b_lo,b_hi,bh,n0,c_local); break;
      case 3: phase1<2,2,2>(act2,ldsw,t,s,b_lo,b_hi,bh,n0,c_local); break;
      case 4: phase1<3,1,2>(act2,ldsw,t,s,b_lo,b_hi,bh,n0,c_local); break;
      case 5: phase1<3,2,2>(act2,ldsw,t,s,b_lo,b_hi,bh,n0,c_local); break;
      default:phase1<3,3,2>(act2,ldsw,t,s,b_lo,b_hi,bh,n0,c_local); break;
    }
  } else {
    switch(q){
      case 0: phase1<2,1,3>(act2,ldsw,t,s,b_lo,b_hi,bh,n0,c_local); break;
      case 1: phase1<2,2,3>(act2,ldsw,t,s,b_lo,b_hi,bh,n0,c_local); break;
      case 2: phase1<3,0,3>(act2,ldsw,t,s,b_lo,b_hi,bh,n0,c_local); break;
      case 3: phase1<3,1,3>(act2,ldsw,t,s,b_lo,b_hi,bh,n0,c_local); break;
      case 4: phase1<3,2,3>(act2,ldsw,t,s,b_lo,b_hi,bh,n0,c_local); break;
      default:phase1<3,3,3>(act2,ldsw,t,s,b_lo,b_hi,bh,n0,c_local); break;
    }
  }
}

template<int L>
DEVFN void k3_gemm(int n0, const float2* __restrict__ act2,
                   const short* __restrict__ A_l, float* __restrict__ out,
                   unsigned* lds){
  constexpr int NP = 2*L+1;
  constexpr int NT = NTRI(L);
  constexpr int pitchA = 2*MLs(L);         // A row pitch in bf16 elements
  const int tid = threadIdx.x;
  const int lane = tid & 63, wsub = tid >> 6;
  const int col = lane & 15, quad = lane >> 4;
  const int nh = wsub & 1, mh = wsub >> 1; // n-half / real-imag half
  const int c_local = tid & 127, bh = tid >> 7;
  const int b_lo = n0 / NP;
  const int b_hi = (n0 + 31) / NP;

  f32x4 acc = {0.f,0.f,0.f,0.f};
  const short* Ar = A_l + (size_t)(col + mh*16) * pitchA + quad*8;
  const int lds_rd = (nh*16 + col)*LPITCH + quad*4;   // word offset

  for(int chunk = 0; chunk < 2*NT; ++chunk){
    const int q = chunk >> 1, half = chunk & 1;
    const int ch = half*128 + c_local;     // channel within triple
    const int t = ch >> 4, s = ch & 15;
    unsigned* buf = lds + (chunk & 1)*(32*LPITCH);
    p1_dispatch<L>(q, act2, buf, t, s, b_lo, b_hi, bh, n0, c_local);
    __syncthreads();                       // single barrier (dbuf handles WAR)
    const int kbase = q*512 + half*256;    // A column base (bf16 elements)
    const char* ldsb = (const char*)(buf + lds_rd);
    #pragma unroll
    for(int ks=0; ks<8; ++ks){
      bf16x8 a = *(const bf16x8*)(Ar + kbase + ks*32);
      bf16x8 b = *(const bf16x8*)(ldsb + ks*64);
      acc = __builtin_amdgcn_mfma_f32_16x16x32_bf16(a, b, acc, 0, 0, 0);
    }
  }
  // epilogue: D col=lane&15 -> n, row=quad*4+reg -> o; mh selects re/im float
  const int n = n0 + nh*16 + col;
  const int b = n / NP, p = n % NP;
  #pragma unroll
  for(int i=0;i<4;++i){
    const int o = quad*4 + i;
    out[((size_t)b*256 + AOFF(L) + o*NP + p)*2 + mh] = acc[i];
  }
}

__global__ __launch_bounds__(256) void k_gemm(const float* __restrict__ act,
                                              const short* __restrict__ A,
                                              float* __restrict__ out){
  __shared__ unsigned lds[2*32*LPITCH];    // 36864 B double buffer
  const int bid = blockIdx.x;              // 1024 = 64(l0)+192(l1)+320(l2)+448(l3)
  const float2* act2 = (const float2*)act;
  if(bid < 64)       k3_gemm<0>((bid      )*32, act2, A + ABASE(0), out, lds);
  else if(bid < 256) k3_gemm<1>((bid - 64 )*32, act2, A + ABASE(1), out, lds);
  else if(bid < 576) k3_gemm<2>((bid - 256)*32, act2, A + ABASE(2), out, lds);
  else               k3_gemm<3>((bid - 576)*32, act2, A + ABASE(3), out, lds);
}

// ================= host launch =================
extern "C" void kernel_launch(void* const* d_in, const int* in_sizes, int n_in,
                              void* d_out, int out_size, void* d_ws, size_t ws_size,
                              hipStream_t stream) {
  const float* act = (const float*)d_in[0];   // (2048,256,2) f32
  const float* W   = (const float*)d_in[1];   // (94208,2) f32
  const float* bn  = (const float*)d_in[2];   // (5888,) f32
  float* out = (float*)d_out;                 // (2048,256,2) f32

  float* sumsq = (float*)d_ws;                          // 5888 f32
  short* A     = (short*)((char*)d_ws + 24576);         // 376832 bf16 (754 KB)

  hipMemsetAsync(sumsq, 0, 5888*sizeof(float), stream);
  hipLaunchKernelGGL(k_sumsq,  dim3(23*128), dim3(256), 0, stream, act, sumsq);
  hipLaunchKernelGGL(k_buildA, dim3(23),     dim3(256), 0, stream, W, bn, sumsq, A);
  hipLaunchKernelGGL(k_gemm,   dim3(1024),   dim3(256), 0, stream, act, A, out);
}

// Round 4
// 193.592 us; speedup vs baseline: 5.0557x; 1.0869x over previous
//
#include <hip/hip_runtime.h>
#include <math.h>

typedef __attribute__((ext_vector_type(8))) short bf16x8;
typedef __attribute__((ext_vector_type(4))) float f32x4;

// ================= compile-time Clebsch-Gordan tables =================
constexpr double cfact(int n){ double r=1.0; for(int i=2;i<=n;++i) r*=(double)i; return r; }
constexpr double csqrt_(double x){ double g=(x>1.0)?x:1.0; for(int i=0;i<100;++i) g=0.5*(g+x/g); return g; }
constexpr double cg_coef_(int l1,int m1,int l2,int m2,int l,int m){
  double pre = csqrt_((double)(2*l+1)*cfact(l1+l2-l)*cfact(l1-l2+l)*cfact(-l1+l2+l)/cfact(l1+l2+l+1));
  pre = pre*csqrt_(cfact(l+m)*cfact(l-m)*cfact(l1-m1)*cfact(l1+m1)*cfact(l2-m2)*cfact(l2+m2));
  double s=0.0;
  for(int k=0;k<=l1+l2-l;++k){
    int d0=k,d1=l1+l2-l-k,d2=l1-m1-k,d3=l2+m2-k,d4=l-l2+m1+k,d5=l-l1-m2+k;
    if(d0<0||d1<0||d2<0||d3<0||d4<0||d5<0) continue;
    double den=cfact(d0)*cfact(d1)*cfact(d2)*cfact(d3)*cfact(d4)*cfact(d5);
    s+=((k&1)?-1.0:1.0)/den;
  }
  return pre*s;
}
struct CGList{ int n; float coef[64]; int mi[64]; int ni[64]; int pi[64]; };
constexpr CGList build_cg(int l1,int l2,int l){
  CGList T{};
  for(int i=0;i<2*l1+1;++i){
    for(int j=0;j<2*l2+1;++j){
      int m1=i-l1, m2=j-l2, m=m1+m2;
      if(m<-l||m>l) continue;
      double c=cg_coef_(l1,m1,l2,m2,l,m);
      if(c>1e-12||c<-1e-12){
        T.coef[T.n]=(float)c; T.mi[T.n]=i; T.ni[T.n]=j; T.pi[T.n]=m+l; T.n++;
      }
    }
  }
  return T;
}

// ================= layout constants =================
__device__ __host__ constexpr int AOFF(int l){ return l==0?0: l==1?16: l==2?64:144; }
__device__ __host__ constexpr int MLs(int l){ return l==0?1024: l==1?1536: l==2?1792:1536; }
__device__ __host__ constexpr int WOFF(int l){ return l==0?0: l==1?16384: l==2?40960:69632; }
__device__ __host__ constexpr int SOFF(int l){ return l==0?0: l==1?1024: l==2?2560:4352; }
__device__ __host__ constexpr int NTRI(int l){ return l==0?4: l==1?6: l==2?7:6; }
__device__ __host__ constexpr int ABASE(int l){ return l==0?0: l==1?65536: l==2?163840:278528; }

#define DEVFN __device__ __forceinline__
#define LPITCH 144   // LDS row pitch in words; conflicts measured ~4 cyc/b128 read regardless of pitch (noise)

DEVFN unsigned f2bf2(float x, float y){
  unsigned ux = __float_as_uint(x); ux = (ux + 0x7FFFu + ((ux>>16)&1u)) >> 16;
  unsigned uy = __float_as_uint(y); uy = (uy + 0x7FFFu + ((uy>>16)&1u)) >> 16;
  return (ux & 0xFFFFu) | (uy << 16);
}

template<int L1,int L2,int L>
DEVFN void cg_accum(const float2* F1, const float2* F2, float2* mid){
  constexpr CGList T = build_cg(L1,L2,L);
  #pragma unroll
  for(int e=0;e<T.n;++e){
    const float c = T.coef[e];
    const float2 a = F1[T.mi[e]];
    const float2 b = F2[T.ni[e]];
    float pr = a.x*b.x - a.y*b.y;
    float pim= a.x*b.y + a.y*b.x;
    mid[T.pi[e]].x += c*pr;
    mid[T.pi[e]].y += c*pim;
  }
}

// ===== K1: per-channel sum of |mid|^2; 2 channels/thread sharing F2 =====
template<int L1,int L2,int L>
DEVFN void k1_body(const float2* __restrict__ act2, int b0, int t, int s,
                   float& ssa, float& ssb){
  constexpr int N1=2*L1+1, N2=2*L2+1, NP=2*L+1;
  #pragma unroll 2
  for(int bi=0;bi<8;++bi){
    const float2* arow = act2 + (size_t)(b0+bi)*256;
    float2 F1a[N1], F1b[N1], F2[N2], mida[NP], midb[NP];
    #pragma unroll
    for(int m=0;m<N1;++m){
      F1a[m]=arow[AOFF(L1)+t*N1+m];
      F1b[m]=arow[AOFF(L1)+(t+8)*N1+m];
    }
    #pragma unroll
    for(int n=0;n<N2;++n) F2[n]=arow[AOFF(L2)+s*N2+n];
    #pragma unroll
    for(int p=0;p<NP;++p){ mida[p]=make_float2(0.f,0.f); midb[p]=make_float2(0.f,0.f); }
    cg_accum<L1,L2,L>(F1a,F2,mida);
    cg_accum<L1,L2,L>(F1b,F2,midb);
    #pragma unroll
    for(int p=0;p<NP;++p){
      ssa += mida[p].x*mida[p].x + mida[p].y*mida[p].y;
      ssb += midb[p].x*midb[p].x + midb[p].y*midb[p].y;
    }
  }
}

__global__ __launch_bounds__(256) void k_sumsq(const float* __restrict__ act, float* __restrict__ sumsq){
  int bid=blockIdx.x;            // 23 triples * 128 chunks = 2944 blocks
  int ti = bid>>7;
  int wsub = threadIdx.x>>7;                 // 2 b-offsets
  int b0 = (bid&127)*16 + wsub*8;
  int t = (threadIdx.x>>4)&7, s = threadIdx.x&15;  // channels (t,s),(t+8,s)
  const float2* act2=(const float2*)act;
  float ssa=0.f, ssb=0.f;
  switch(ti){
    case 0:  k1_body<0,0,0>(act2,b0,t,s,ssa,ssb); break;
    case 1:  k1_body<1,1,0>(act2,b0,t,s,ssa,ssb); break;
    case 2:  k1_body<2,2,0>(act2,b0,t,s,ssa,ssb); break;
    case 3:  k1_body<3,3,0>(act2,b0,t,s,ssa,ssb); break;
    case 4:  k1_body<1,0,1>(act2,b0,t,s,ssa,ssb); break;
    case 5:  k1_body<1,1,1>(act2,b0,t,s,ssa,ssb); break;
    case 6:  k1_body<2,1,1>(act2,b0,t,s,ssa,ssb); break;
    case 7:  k1_body<2,2,1>(act2,b0,t,s,ssa,ssb); break;
    case 8:  k1_body<3,2,1>(act2,b0,t,s,ssa,ssb); break;
    case 9:  k1_body<3,3,1>(act2,b0,t,s,ssa,ssb); break;
    case 10: k1_body<1,1,2>(act2,b0,t,s,ssa,ssb); break;
    case 11: k1_body<2,0,2>(act2,b0,t,s,ssa,ssb); break;
    case 12: k1_body<2,1,2>(act2,b0,t,s,ssa,ssb); break;
    case 13: k1_body<2,2,2>(act2,b0,t,s,ssa,ssb); break;
    case 14: k1_body<3,1,2>(act2,b0,t,s,ssa,ssb); break;
    case 15: k1_body<3,2,2>(act2,b0,t,s,ssa,ssb); break;
    case 16: k1_body<3,3,2>(act2,b0,t,s,ssa,ssb); break;
    case 17: k1_body<2,1,3>(act2,b0,t,s,ssa,ssb); break;
    case 18: k1_body<2,2,3>(act2,b0,t,s,ssa,ssb); break;
    case 19: k1_body<3,0,3>(act2,b0,t,s,ssa,ssb); break;
    case 20: k1_body<3,1,3>(act2,b0,t,s,ssa,ssb); break;
    case 21: k1_body<3,2,3>(act2,b0,t,s,ssa,ssb); break;
    default: k1_body<3,3,3>(act2,b0,t,s,ssa,ssb); break;
  }
  atomicAdd(&sumsq[ti*256 + t*16 + s], ssa);
  atomicAdd(&sumsq[ti*256 + (t+8)*16 + s], ssb);
}

// ============ K2: scale + build bf16 A matrices (scale folded into W) =======
__global__ __launch_bounds__(256) void k_buildA(const float* __restrict__ W,
                                                const float* __restrict__ bn,
                                                const float* __restrict__ sumsq,
                                                short* __restrict__ A){
  int idx = blockIdx.x*256 + threadIdx.x;   // 5888 channels
  if(idx>=5888) return;
  int l = (idx<1024)?0 : (idx<2560)?1 : (idx<4352)?2 : 3;
  float divi = (l==0)?(1.f/2048.f) : (l==1)?(1.f/6144.f) : (l==2)?(1.f/10240.f) : (1.f/14336.f);
  float bstd = sqrtf(sumsq[idx]*divi);
  float nstd = 0.5f*(bn[idx]+bstd);
  float s = 1.f/(nstd+1e-5f);
  int c = idx - SOFF(l);
  int Ml = MLs(l);
  const float2* wbase = (const float2*)W + WOFF(l) + c;
  unsigned* Aw = (unsigned*)(A + ABASE(l));   // row pitch = Ml words (2*Ml bf16)
  for(int o=0;o<16;++o){
    float2 w = wbase[(size_t)o*Ml];
    Aw[(size_t)o*Ml + c]      = f2bf2(w.x*s, -w.y*s);
    Aw[(size_t)(o+16)*Ml + c] = f2bf2(w.y*s,  w.x*s);
  }
}

// ================= K3: fused mid-recompute + MFMA GEMM =================
// Phase1: thread handles channels (c0, c0+64) of the 128-channel k-chunk
// (sharing the F2 load), 4 b-offsets via bh4. Dbuf LDS, 1 barrier/chunk.
template<int L1,int L2,int L>
DEVFN void phase1(const float2* __restrict__ act2, unsigned* ldsw,
                  int half, int c0, int bh4, int b_lo, int b_hi, int n0){
  constexpr int N1=2*L1+1, N2=2*L2+1, NP=2*L+1;
  const int s  = c0 & 15;
  const int t1 = half*8 + (c0>>4);   // c0>>4 in [0,4)
  const int t2 = t1 + 4;
  for(int b = b_lo + bh4; b <= b_hi; b += 4){
    const float2* arow = act2 + (size_t)b*256;
    float2 F1a[N1], F1b[N1], F2[N2], mida[NP], midb[NP];
    #pragma unroll
    for(int m=0;m<N1;++m){
      F1a[m]=arow[AOFF(L1)+t1*N1+m];
      F1b[m]=arow[AOFF(L1)+t2*N1+m];
    }
    #pragma unroll
    for(int n=0;n<N2;++n) F2[n]=arow[AOFF(L2)+s*N2+n];
    #pragma unroll
    for(int p=0;p<NP;++p){ mida[p]=make_float2(0.f,0.f); midb[p]=make_float2(0.f,0.f); }
    cg_accum<L1,L2,L>(F1a,F2,mida);
    cg_accum<L1,L2,L>(F1b,F2,midb);
    int nb = b*NP - n0;
    #pragma unroll
    for(int p=0;p<NP;++p){
      int n = nb + p;
      if(n>=0 && n<32){
        ldsw[n*LPITCH + c0]      = f2bf2(mida[p].x, mida[p].y);
        ldsw[n*LPITCH + c0 + 64] = f2bf2(midb[p].x, midb[p].y);
      }
    }
  }
}

template<int L>
DEVFN void p1_dispatch(int q, int half, const float2* __restrict__ act2, unsigned* ldsw,
                       int c0,int bh4,int b_lo,int b_hi,int n0){
  if constexpr(L==0){
    switch(q){
      case 0: phase1<0,0,0>(act2,ldsw,half,c0,bh4,b_lo,b_hi,n0); break;
      case 1: phase1<1,1,0>(act2,ldsw,half,c0,bh4,b_lo,b_hi,n0); break;
      case 2: phase1<2,2,0>(act2,ldsw,half,c0,bh4,b_lo,b_hi,n0); break;
      default:phase1<3,3,0>(act2,ldsw,half,c0,bh4,b_lo,b_hi,n0); break;
    }
  } else if constexpr(L==1){
    switch(q){
      case 0: phase1<1,0,1>(act2,ldsw,half,c0,bh4,b_lo,b_hi,n0); break;
      case 1: phase1<1,1,1>(act2,ldsw,half,c0,bh4,b_lo,b_hi,n0); break;
      case 2: phase1<2,1,1>(act2,ldsw,half,c0,bh4,b_lo,b_hi,n0); break;
      case 3: phase1<2,2,1>(act2,ldsw,half,c0,bh4,b_lo,b_hi,n0); break;
      case 4: phase1<3,2,1>(act2,ldsw,half,c0,bh4,b_lo,b_hi,n0); break;
      default:phase1<3,3,1>(act2,ldsw,half,c0,bh4,b_lo,b_hi,n0); break;
    }
  } else if constexpr(L==2){
    switch(q){
      case 0: phase1<1,1,2>(act2,ldsw,half,c0,bh4,b_lo,b_hi,n0); break;
      case 1: phase1<2,0,2>(act2,ldsw,half,c0,bh4,b_lo,b_hi,n0); break;
      case 2: phase1<2,1,2>(act2,ldsw,half,c0,bh4,b_lo,b_hi,n0); break;
      case 3: phase1<2,2,2>(act2,ldsw,half,c0,bh4,b_lo,b_hi,n0); break;
      case 4: phase1<3,1,2>(act2,ldsw,half,c0,bh4,b_lo,b_hi,n0); break;
      case 5: phase1<3,2,2>(act2,ldsw,half,c0,bh4,b_lo,b_hi,n0); break;
      default:phase1<3,3,2>(act2,ldsw,half,c0,bh4,b_lo,b_hi,n0); break;
    }
  } else {
    switch(q){
      case 0: phase1<2,1,3>(act2,ldsw,half,c0,bh4,b_lo,b_hi,n0); break;
      case 1: phase1<2,2,3>(act2,ldsw,half,c0,bh4,b_lo,b_hi,n0); break;
      case 2: phase1<3,0,3>(act2,ldsw,half,c0,bh4,b_lo,b_hi,n0); break;
      case 3: phase1<3,1,3>(act2,ldsw,half,c0,bh4,b_lo,b_hi,n0); break;
      case 4: phase1<3,2,3>(act2,ldsw,half,c0,bh4,b_lo,b_hi,n0); break;
      default:phase1<3,3,3>(act2,ldsw,half,c0,bh4,b_lo,b_hi,n0); break;
    }
  }
}

template<int L>
DEVFN void k3_gemm(int n0, const float2* __restrict__ act2,
                   const short* __restrict__ A_l, float* __restrict__ out,
                   unsigned* lds){
  constexpr int NP = 2*L+1;
  constexpr int NT = NTRI(L);
  constexpr int pitchA = 2*MLs(L);         // A row pitch in bf16 elements
  const int tid = threadIdx.x;
  const int lane = tid & 63, wsub = tid >> 6;
  const int col = lane & 15, quad = lane >> 4;
  const int nh = wsub & 1, mh = wsub >> 1; // n-half / real-imag half
  const int c0 = tid & 63, bh4 = tid >> 6; // phase-1 mapping
  const int b_lo = n0 / NP;
  const int b_hi = (n0 + 31) / NP;

  f32x4 acc = {0.f,0.f,0.f,0.f};
  const short* Ar = A_l + (size_t)(col + mh*16) * pitchA + quad*8;
  const int lds_rd = (nh*16 + col)*LPITCH + quad*4;   // word offset

  for(int chunk = 0; chunk < 2*NT; ++chunk){
    const int q = chunk >> 1, half = chunk & 1;
    unsigned* buf = lds + (chunk & 1)*(32*LPITCH);
    p1_dispatch<L>(q, half, act2, buf, c0, bh4, b_lo, b_hi, n0);
    __syncthreads();                       // single barrier (dbuf handles WAR)
    const int kbase = q*512 + half*256;    // A column base (bf16 elements)
    const char* ldsb = (const char*)(buf + lds_rd);
    #pragma unroll
    for(int ks=0; ks<8; ++ks){
      bf16x8 a = *(const bf16x8*)(Ar + kbase + ks*32);
      bf16x8 b = *(const bf16x8*)(ldsb + ks*64);
      acc = __builtin_amdgcn_mfma_f32_16x16x32_bf16(a, b, acc, 0, 0, 0);
    }
  }
  // epilogue: D col=lane&15 -> n, row=quad*4+reg -> o; mh selects re/im float
  const int n = n0 + nh*16 + col;
  const int b = n / NP, p = n % NP;
  #pragma unroll
  for(int i=0;i<4;++i){
    const int o = quad*4 + i;
    out[((size_t)b*256 + AOFF(L) + o*NP + p)*2 + mh] = acc[i];
  }
}

__global__ __launch_bounds__(256) void k_gemm(const float* __restrict__ act,
                                              const short* __restrict__ A,
                                              float* __restrict__ out){
  __shared__ unsigned lds[2*32*LPITCH];    // 36864 B double buffer
  const int bid = blockIdx.x;              // 1024 = 64(l0)+192(l1)+320(l2)+448(l3)
  const float2* act2 = (const float2*)act;
  if(bid < 64)       k3_gemm<0>((bid      )*32, act2, A + ABASE(0), out, lds);
  else if(bid < 256) k3_gemm<1>((bid - 64 )*32, act2, A + ABASE(1), out, lds);
  else if(bid < 576) k3_gemm<2>((bid - 256)*32, act2, A + ABASE(2), out, lds);
  else               k3_gemm<3>((bid - 576)*32, act2, A + ABASE(3), out, lds);
}

// ================= host launch =================
extern "C" void kernel_launch(void* const* d_in, const int* in_sizes, int n_in,
                              void* d_out, int out_size, void* d_ws, size_t ws_size,
                              hipStream_t stream) {
  const float* act = (const float*)d_in[0];   // (2048,256,2) f32
  const float* W   = (const float*)d_in[1];   // (94208,2) f32
  const float* bn  = (const float*)d_in[2];   // (5888,) f32
  float* out = (float*)d_out;                 // (2048,256,2) f32

  float* sumsq = (float*)d_ws;                          // 5888 f32
  short* A     = (short*)((char*)d_ws + 24576);         // 376832 bf16 (754 KB)

  hipMemsetAsync(sumsq, 0, 5888*sizeof(float), stream);
  hipLaunchKernelGGL(k_sumsq,  dim3(23*128), dim3(256), 0, stream, act, sumsq);
  hipLaunchKernelGGL(k_buildA, dim3(23),     dim3(256), 0, stream, W, bn, sumsq, A);
  hipLaunchKernelGGL(k_gemm,   dim3(1024),   dim3(256), 0, stream, act, A, out);
}

// Round 5
// 191.889 us; speedup vs baseline: 5.1005x; 1.0089x over previous
//
#include <hip/hip_runtime.h>
#include <math.h>

typedef __attribute__((ext_vector_type(8))) short bf16x8;
typedef __attribute__((ext_vector_type(4))) float f32x4;

// ================= compile-time Clebsch-Gordan tables =================
constexpr double cfact(int n){ double r=1.0; for(int i=2;i<=n;++i) r*=(double)i; return r; }
constexpr double csqrt_(double x){ double g=(x>1.0)?x:1.0; for(int i=0;i<100;++i) g=0.5*(g+x/g); return g; }
constexpr double cg_coef_(int l1,int m1,int l2,int m2,int l,int m){
  double pre = csqrt_((double)(2*l+1)*cfact(l1+l2-l)*cfact(l1-l2+l)*cfact(-l1+l2+l)/cfact(l1+l2+l+1));
  pre = pre*csqrt_(cfact(l+m)*cfact(l-m)*cfact(l1-m1)*cfact(l1+m1)*cfact(l2-m2)*cfact(l2+m2));
  double s=0.0;
  for(int k=0;k<=l1+l2-l;++k){
    int d0=k,d1=l1+l2-l-k,d2=l1-m1-k,d3=l2+m2-k,d4=l-l2+m1+k,d5=l-l1-m2+k;
    if(d0<0||d1<0||d2<0||d3<0||d4<0||d5<0) continue;
    double den=cfact(d0)*cfact(d1)*cfact(d2)*cfact(d3)*cfact(d4)*cfact(d5);
    s+=((k&1)?-1.0:1.0)/den;
  }
  return pre*s;
}
struct CGList{ int n; float coef[64]; int mi[64]; int ni[64]; int pi[64]; };
constexpr CGList build_cg(int l1,int l2,int l){
  CGList T{};
  for(int i=0;i<2*l1+1;++i){
    for(int j=0;j<2*l2+1;++j){
      int m1=i-l1, m2=j-l2, m=m1+m2;
      if(m<-l||m>l) continue;
      double c=cg_coef_(l1,m1,l2,m2,l,m);
      if(c>1e-12||c<-1e-12){
        T.coef[T.n]=(float)c; T.mi[T.n]=i; T.ni[T.n]=j; T.pi[T.n]=m+l; T.n++;
      }
    }
  }
  return T;
}

// ================= layout constants =================
__device__ __host__ constexpr int AOFF(int l){ return l==0?0: l==1?16: l==2?64:144; }
__device__ __host__ constexpr int MLs(int l){ return l==0?1024: l==1?1536: l==2?1792:1536; }
__device__ __host__ constexpr int WOFF(int l){ return l==0?0: l==1?16384: l==2?40960:69632; }
__device__ __host__ constexpr int SOFF(int l){ return l==0?0: l==1?1024: l==2?2560:4352; }
__device__ __host__ constexpr int NTRI(int l){ return l==0?4: l==1?6: l==2?7:6; }
__device__ __host__ constexpr int ABASE(int l){ return l==0?0: l==1?65536: l==2?163840:278528; }
// mid storage: per-l base in 4B words; row = n (b*NP+p), row pitch = MLs(l) words
__device__ __host__ constexpr size_t MBW(int l){ return l==0?0 : l==1?2097152 : l==2?11534336 : 29884416; }
// total mid words = 51,904,512 (207.6 MB); placed at +1 MiB in ws
#define MID_OFF 1048576
#define MID_BYTES ((size_t)51904512*4)

#define DEVFN __device__ __forceinline__
#define LPITCH 144   // old-path LDS pitch

DEVFN unsigned f2bf2(float x, float y){
  unsigned ux = __float_as_uint(x); ux = (ux + 0x7FFFu + ((ux>>16)&1u)) >> 16;
  unsigned uy = __float_as_uint(y); uy = (uy + 0x7FFFu + ((uy>>16)&1u)) >> 16;
  return (ux & 0xFFFFu) | (uy << 16);
}

template<int L1,int L2,int L>
DEVFN void cg_accum(const float2* F1, const float2* F2, float2* mid){
  constexpr CGList T = build_cg(L1,L2,L);
  #pragma unroll
  for(int e=0;e<T.n;++e){
    const float c = T.coef[e];
    const float2 a = F1[T.mi[e]];
    const float2 b = F2[T.ni[e]];
    float pr = a.x*b.x - a.y*b.y;
    float pim= a.x*b.y + a.y*b.x;
    mid[T.pi[e]].x += c*pr;
    mid[T.pi[e]].y += c*pim;
  }
}

// ===== K1: per-channel sum |mid|^2 + (optional) bf16 mid store to HBM =====
template<int L1,int L2,int L,int Q>
DEVFN void k1_body(const float2* __restrict__ act2, int b0, int t, int s,
                   float& ssa, float& ssb, unsigned* __restrict__ midw){
  constexpr int N1=2*L1+1, N2=2*L2+1, NP=2*L+1, Ml=MLs(L);
  const int c1 = t*16 + s;                  // second channel at c1+128
  unsigned* midq = midw ? (midw + MBW(L) + Q*256) : nullptr;
  #pragma unroll 2
  for(int bi=0;bi<8;++bi){
    const int b = b0 + bi;
    const float2* arow = act2 + (size_t)b*256;
    float2 F1a[N1], F1b[N1], F2[N2], mida[NP], midb[NP];
    #pragma unroll
    for(int m=0;m<N1;++m){
      F1a[m]=arow[AOFF(L1)+t*N1+m];
      F1b[m]=arow[AOFF(L1)+(t+8)*N1+m];
    }
    #pragma unroll
    for(int n=0;n<N2;++n) F2[n]=arow[AOFF(L2)+s*N2+n];
    #pragma unroll
    for(int p=0;p<NP;++p){ mida[p]=make_float2(0.f,0.f); midb[p]=make_float2(0.f,0.f); }
    cg_accum<L1,L2,L>(F1a,F2,mida);
    cg_accum<L1,L2,L>(F1b,F2,midb);
    #pragma unroll
    for(int p=0;p<NP;++p){
      ssa += mida[p].x*mida[p].x + mida[p].y*mida[p].y;
      ssb += midb[p].x*midb[p].x + midb[p].y*midb[p].y;
    }
    if(midq){
      const size_t nrow = (size_t)b*NP;
      #pragma unroll
      for(int p=0;p<NP;++p){
        midq[(nrow+p)*Ml + c1]       = f2bf2(mida[p].x, mida[p].y);
        midq[(nrow+p)*Ml + c1 + 128] = f2bf2(midb[p].x, midb[p].y);
      }
    }
  }
}

__global__ __launch_bounds__(256) void k_sumsq(const float* __restrict__ act,
                                               float* __restrict__ sumsq,
                                               unsigned* __restrict__ midw){
  int bid=blockIdx.x;            // 23 triples * 128 chunks = 2944 blocks
  int ti = bid>>7;
  int wsub = threadIdx.x>>7;                 // 2 b-offsets
  int b0 = (bid&127)*16 + wsub*8;
  int t = (threadIdx.x>>4)&7, s = threadIdx.x&15;  // channels (t,s),(t+8,s)
  const float2* act2=(const float2*)act;
  float ssa=0.f, ssb=0.f;
  switch(ti){
    case 0:  k1_body<0,0,0,0>(act2,b0,t,s,ssa,ssb,midw); break;
    case 1:  k1_body<1,1,0,1>(act2,b0,t,s,ssa,ssb,midw); break;
    case 2:  k1_body<2,2,0,2>(act2,b0,t,s,ssa,ssb,midw); break;
    case 3:  k1_body<3,3,0,3>(act2,b0,t,s,ssa,ssb,midw); break;
    case 4:  k1_body<1,0,1,0>(act2,b0,t,s,ssa,ssb,midw); break;
    case 5:  k1_body<1,1,1,1>(act2,b0,t,s,ssa,ssb,midw); break;
    case 6:  k1_body<2,1,1,2>(act2,b0,t,s,ssa,ssb,midw); break;
    case 7:  k1_body<2,2,1,3>(act2,b0,t,s,ssa,ssb,midw); break;
    case 8:  k1_body<3,2,1,4>(act2,b0,t,s,ssa,ssb,midw); break;
    case 9:  k1_body<3,3,1,5>(act2,b0,t,s,ssa,ssb,midw); break;
    case 10: k1_body<1,1,2,0>(act2,b0,t,s,ssa,ssb,midw); break;
    case 11: k1_body<2,0,2,1>(act2,b0,t,s,ssa,ssb,midw); break;
    case 12: k1_body<2,1,2,2>(act2,b0,t,s,ssa,ssb,midw); break;
    case 13: k1_body<2,2,2,3>(act2,b0,t,s,ssa,ssb,midw); break;
    case 14: k1_body<3,1,2,4>(act2,b0,t,s,ssa,ssb,midw); break;
    case 15: k1_body<3,2,2,5>(act2,b0,t,s,ssa,ssb,midw); break;
    case 16: k1_body<3,3,2,6>(act2,b0,t,s,ssa,ssb,midw); break;
    case 17: k1_body<2,1,3,0>(act2,b0,t,s,ssa,ssb,midw); break;
    case 18: k1_body<2,2,3,1>(act2,b0,t,s,ssa,ssb,midw); break;
    case 19: k1_body<3,0,3,2>(act2,b0,t,s,ssa,ssb,midw); break;
    case 20: k1_body<3,1,3,3>(act2,b0,t,s,ssa,ssb,midw); break;
    case 21: k1_body<3,2,3,4>(act2,b0,t,s,ssa,ssb,midw); break;
    default: k1_body<3,3,3,5>(act2,b0,t,s,ssa,ssb,midw); break;
  }
  atomicAdd(&sumsq[ti*256 + t*16 + s], ssa);
  atomicAdd(&sumsq[ti*256 + (t+8)*16 + s], ssb);
}

// ============ K2: scale + build bf16 A matrices (scale folded into W) =======
__global__ __launch_bounds__(256) void k_buildA(const float* __restrict__ W,
                                                const float* __restrict__ bn,
                                                const float* __restrict__ sumsq,
                                                short* __restrict__ A){
  int idx = blockIdx.x*256 + threadIdx.x;   // 5888 channels
  if(idx>=5888) return;
  int l = (idx<1024)?0 : (idx<2560)?1 : (idx<4352)?2 : 3;
  float divi = (l==0)?(1.f/2048.f) : (l==1)?(1.f/6144.f) : (l==2)?(1.f/10240.f) : (1.f/14336.f);
  float bstd = sqrtf(sumsq[idx]*divi);
  float nstd = 0.5f*(bn[idx]+bstd);
  float s = 1.f/(nstd+1e-5f);
  int c = idx - SOFF(l);
  int Ml = MLs(l);
  const float2* wbase = (const float2*)W + WOFF(l) + c;
  unsigned* Aw = (unsigned*)(A + ABASE(l));   // row pitch = Ml words (2*Ml bf16)
  for(int o=0;o<16;++o){
    float2 w = wbase[(size_t)o*Ml];
    Aw[(size_t)o*Ml + c]      = f2bf2(w.x*s, -w.y*s);
    Aw[(size_t)(o+16)*Ml + c] = f2bf2(w.y*s,  w.x*s);
  }
}

// ======== K3-stream: GEMM consuming stored mid (primary path) =========
// Block: one l, 32-row n-window. Per 256-bf16 k-chunk: 256 threads load
// 16 KB of mid (coalesced 16 B), XOR-swizzled ds_write_b128; 4 waves x
// (nh, re/im) 16x16 tiles, 8 MFMA each. Dbuf, 1 barrier/chunk.
template<int L>
DEVFN void k3_stream(int n0, const unsigned* __restrict__ midl,
                     const short* __restrict__ A_l, float* __restrict__ out,
                     unsigned* lds){
  constexpr int NP = 2*L+1;
  constexpr int Ml = MLs(L);
  constexpr int pitchA = 2*Ml;
  constexpr int C = 2*NTRI(L);
  const int tid = threadIdx.x;
  const int lane = tid & 63, wsub = tid >> 6;
  const int col = lane & 15, quad = lane >> 4;
  const int nh = wsub & 1, mh = wsub >> 1;
  const int swc = col & 7;

  f32x4 acc = {0.f,0.f,0.f,0.f};
  const short* Ar = A_l + (size_t)(col + mh*16) * pitchA + quad*8;

  // per-thread load slots: j=0..3 -> global 16B chunk g=j*256+tid of the tile
  const unsigned* gp[4]; int loff[4];
  #pragma unroll
  for(int j=0;j<4;++j){
    int g = j*256 + tid;
    int r = g >> 5, gc = g & 31;
    gp[j]   = midl + (size_t)(n0+r)*Ml + gc*4;
    loff[j] = r*512 + ((gc ^ (r&7))*16);    // bytes, swizzled slot
  }
  const char* bbase0 = (const char*)lds + (nh*16+col)*512;

  for(int c=0;c<C;++c){
    unsigned* buf = lds + (c&1)*4096;       // words
    #pragma unroll
    for(int j=0;j<4;++j){
      bf16x8 v = *(const bf16x8*)(gp[j] + c*128);
      *(bf16x8*)((char*)buf + loff[j]) = v;
    }
    __syncthreads();                        // dbuf handles WAR; 1 barrier/chunk
    const short* Ac = Ar + c*256;
    const char* bbase = bbase0 + (c&1)*16384;
    #pragma unroll
    for(int ks=0;ks<8;++ks){
      bf16x8 a = *(const bf16x8*)(Ac + ks*32);
      bf16x8 b = *(const bf16x8*)(bbase + (((ks*4+quad) ^ swc)*16));
      acc = __builtin_amdgcn_mfma_f32_16x16x32_bf16(a, b, acc, 0, 0, 0);
    }
  }
  const int n = n0 + nh*16 + col;
  const int b = n / NP, p = n % NP;
  #pragma unroll
  for(int i=0;i<4;++i){
    const int o = quad*4 + i;
    out[((size_t)b*256 + AOFF(L) + o*NP + p)*2 + mh] = acc[i];
  }
}

__global__ __launch_bounds__(256) void k_gemm_s(const unsigned* __restrict__ midw,
                                                const short* __restrict__ A,
                                                float* __restrict__ out){
  __shared__ unsigned lds[2*32*128];        // 32 KB double buffer
  const int bid = blockIdx.x;               // 1024 = 64+192+320+448
  if(bid < 64)       k3_stream<0>((bid      )*32, midw+MBW(0), A+ABASE(0), out, lds);
  else if(bid < 256) k3_stream<1>((bid - 64 )*32, midw+MBW(1), A+ABASE(1), out, lds);
  else if(bid < 576) k3_stream<2>((bid - 256)*32, midw+MBW(2), A+ABASE(2), out, lds);
  else               k3_stream<3>((bid - 576)*32, midw+MBW(3), A+ABASE(3), out, lds);
}

// ======== K3-recompute: fallback if ws too small for mid ========
template<int L1,int L2,int L>
DEVFN void phase1(const float2* __restrict__ act2, unsigned* ldsw,
                  int half, int c0, int bh4, int b_lo, int b_hi, int n0){
  constexpr int N1=2*L1+1, N2=2*L2+1, NP=2*L+1;
  const int s  = c0 & 15;
  const int t1 = half*8 + (c0>>4);
  const int t2 = t1 + 4;
  for(int b = b_lo + bh4; b <= b_hi; b += 4){
    const float2* arow = act2 + (size_t)b*256;
    float2 F1a[N1], F1b[N1], F2[N2], mida[NP], midb[NP];
    #pragma unroll
    for(int m=0;m<N1;++m){
      F1a[m]=arow[AOFF(L1)+t1*N1+m];
      F1b[m]=arow[AOFF(L1)+t2*N1+m];
    }
    #pragma unroll
    for(int n=0;n<N2;++n) F2[n]=arow[AOFF(L2)+s*N2+n];
    #pragma unroll
    for(int p=0;p<NP;++p){ mida[p]=make_float2(0.f,0.f); midb[p]=make_float2(0.f,0.f); }
    cg_accum<L1,L2,L>(F1a,F2,mida);
    cg_accum<L1,L2,L>(F1b,F2,midb);
    int nb = b*NP - n0;
    #pragma unroll
    for(int p=0;p<NP;++p){
      int n = nb + p;
      if(n>=0 && n<32){
        ldsw[n*LPITCH + c0]      = f2bf2(mida[p].x, mida[p].y);
        ldsw[n*LPITCH + c0 + 64] = f2bf2(midb[p].x, midb[p].y);
      }
    }
  }
}

template<int L>
DEVFN void p1_dispatch(int q, int half, const float2* __restrict__ act2, unsigned* ldsw,
                       int c0,int bh4,int b_lo,int b_hi,int n0){
  if constexpr(L==0){
    switch(q){
      case 0: phase1<0,0,0>(act2,ldsw,half,c0,bh4,b_lo,b_hi,n0); break;
      case 1: phase1<1,1,0>(act2,ldsw,half,c0,bh4,b_lo,b_hi,n0); break;
      case 2: phase1<2,2,0>(act2,ldsw,half,c0,bh4,b_lo,b_hi,n0); break;
      default:phase1<3,3,0>(act2,ldsw,half,c0,bh4,b_lo,b_hi,n0); break;
    }
  } else if constexpr(L==1){
    switch(q){
      case 0: phase1<1,0,1>(act2,ldsw,half,c0,bh4,b_lo,b_hi,n0); break;
      case 1: phase1<1,1,1>(act2,ldsw,half,c0,bh4,b_lo,b_hi,n0); break;
      case 2: phase1<2,1,1>(act2,ldsw,half,c0,bh4,b_lo,b_hi,n0); break;
      case 3: phase1<2,2,1>(act2,ldsw,half,c0,bh4,b_lo,b_hi,n0); break;
      case 4: phase1<3,2,1>(act2,ldsw,half,c0,bh4,b_lo,b_hi,n0); break;
      default:phase1<3,3,1>(act2,ldsw,half,c0,bh4,b_lo,b_hi,n0); break;
    }
  } else if constexpr(L==2){
    switch(q){
      case 0: phase1<1,1,2>(act2,ldsw,half,c0,bh4,b_lo,b_hi,n0); break;
      case 1: phase1<2,0,2>(act2,ldsw,half,c0,bh4,b_lo,b_hi,n0); break;
      case 2: phase1<2,1,2>(act2,ldsw,half,c0,bh4,b_lo,b_hi,n0); break;
      case 3: phase1<2,2,2>(act2,ldsw,half,c0,bh4,b_lo,b_hi,n0); break;
      case 4: phase1<3,1,2>(act2,ldsw,half,c0,bh4,b_lo,b_hi,n0); break;
      case 5: phase1<3,2,2>(act2,ldsw,half,c0,bh4,b_lo,b_hi,n0); break;
      default:phase1<3,3,2>(act2,ldsw,half,c0,bh4,b_lo,b_hi,n0); break;
    }
  } else {
    switch(q){
      case 0: phase1<2,1,3>(act2,ldsw,half,c0,bh4,b_lo,b_hi,n0); break;
      case 1: phase1<2,2,3>(act2,ldsw,half,c0,bh4,b_lo,b_hi,n0); break;
      case 2: phase1<3,0,3>(act2,ldsw,half,c0,bh4,b_lo,b_hi,n0); break;
      case 3: phase1<3,1,3>(act2,ldsw,half,c0,bh4,b_lo,b_hi,n0); break;
      case 4: phase1<3,2,3>(act2,ldsw,half,c0,bh4,b_lo,b_hi,n0); break;
      default:phase1<3,3,3>(act2,ldsw,half,c0,bh4,b_lo,b_hi,n0); break;
    }
  }
}

template<int L>
DEVFN void k3_gemm(int n0, const float2* __restrict__ act2,
                   const short* __restrict__ A_l, float* __restrict__ out,
                   unsigned* lds){
  constexpr int NP = 2*L+1;
  constexpr int NT = NTRI(L);
  constexpr int pitchA = 2*MLs(L);
  const int tid = threadIdx.x;
  const int lane = tid & 63, wsub = tid >> 6;
  const int col = lane & 15, quad = lane >> 4;
  const int nh = wsub & 1, mh = wsub >> 1;
  const int c0 = tid & 63, bh4 = tid >> 6;
  const int b_lo = n0 / NP;
  const int b_hi = (n0 + 31) / NP;

  f32x4 acc = {0.f,0.f,0.f,0.f};
  const short* Ar = A_l + (size_t)(col + mh*16) * pitchA + quad*8;
  const int lds_rd = (nh*16 + col)*LPITCH + quad*4;

  for(int chunk = 0; chunk < 2*NT; ++chunk){
    const int q = chunk >> 1, half = chunk & 1;
    unsigned* buf = lds + (chunk & 1)*(32*LPITCH);
    p1_dispatch<L>(q, half, act2, buf, c0, bh4, b_lo, b_hi, n0);
    __syncthreads();
    const int kbase = q*512 + half*256;
    const char* ldsb = (const char*)(buf + lds_rd);
    #pragma unroll
    for(int ks=0; ks<8; ++ks){
      bf16x8 a = *(const bf16x8*)(Ar + kbase + ks*32);
      bf16x8 b = *(const bf16x8*)(ldsb + ks*64);
      acc = __builtin_amdgcn_mfma_f32_16x16x32_bf16(a, b, acc, 0, 0, 0);
    }
  }
  const int n = n0 + nh*16 + col;
  const int b = n / NP, p = n % NP;
  #pragma unroll
  for(int i=0;i<4;++i){
    const int o = quad*4 + i;
    out[((size_t)b*256 + AOFF(L) + o*NP + p)*2 + mh] = acc[i];
  }
}

__global__ __launch_bounds__(256) void k_gemm(const float* __restrict__ act,
                                              const short* __restrict__ A,
                                              float* __restrict__ out){
  __shared__ unsigned lds[2*32*LPITCH];
  const int bid = blockIdx.x;
  const float2* act2 = (const float2*)act;
  if(bid < 64)       k3_gemm<0>((bid      )*32, act2, A + ABASE(0), out, lds);
  else if(bid < 256) k3_gemm<1>((bid - 64 )*32, act2, A + ABASE(1), out, lds);
  else if(bid < 576) k3_gemm<2>((bid - 256)*32, act2, A + ABASE(2), out, lds);
  else               k3_gemm<3>((bid - 576)*32, act2, A + ABASE(3), out, lds);
}

// ================= host launch =================
extern "C" void kernel_launch(void* const* d_in, const int* in_sizes, int n_in,
                              void* d_out, int out_size, void* d_ws, size_t ws_size,
                              hipStream_t stream) {
  const float* act = (const float*)d_in[0];   // (2048,256,2) f32
  const float* W   = (const float*)d_in[1];   // (94208,2) f32
  const float* bn  = (const float*)d_in[2];   // (5888,) f32
  float* out = (float*)d_out;                 // (2048,256,2) f32

  float* sumsq = (float*)d_ws;                          // 5888 f32
  short* A     = (short*)((char*)d_ws + 24576);         // 376832 bf16 (754 KB)
  const size_t REQ = (size_t)MID_OFF + MID_BYTES;       // ~209 MB
  unsigned* midw = (ws_size >= REQ) ? (unsigned*)((char*)d_ws + MID_OFF) : nullptr;

  hipMemsetAsync(sumsq, 0, 5888*sizeof(float), stream);
  hipLaunchKernelGGL(k_sumsq,  dim3(23*128), dim3(256), 0, stream, act, sumsq, midw);
  hipLaunchKernelGGL(k_buildA, dim3(23),     dim3(256), 0, stream, W, bn, sumsq, A);
  if(midw)
    hipLaunchKernelGGL(k_gemm_s, dim3(1024), dim3(256), 0, stream, (const unsigned*)midw, A, out);
  else
    hipLaunchKernelGGL(k_gemm,   dim3(1024), dim3(256), 0, stream, act, A, out);
}